// Round 6
// baseline (27.873 us; speedup 1.0000x reference)
//
#include <hip/hip_runtime.h>

#define TLEN 1461
#define L2E      1.44269504088896340736f
#define TWO_L2E  2.88539008177792681472f

typedef __bf16 bf16x8 __attribute__((ext_vector_type(8)));
typedef float f32x16 __attribute__((ext_vector_type(16)));

union FragU { unsigned u[4]; bf16x8 f; };

__device__ __forceinline__ float step_fn(float x) {
    // (tanh(5x)+1)/2 = sigmoid(10x) = 1/(1+exp2(-10*log2e*x))
    float e = __builtin_amdgcn_exp2f(x * -14.4269504088896341f);
    return __builtin_amdgcn_rcpf(1.0f + e);
}
__device__ __forceinline__ unsigned cvt_pk_bf16(float lo, float hi) {
    unsigned r;
    asm("v_cvt_pk_bf16_f32 %0, %1, %2" : "=v"(r) : "v"(lo), "v"(hi));
    return r;
}
__device__ __forceinline__ void plswap(unsigned &a, unsigned &b) {
    asm("v_permlane32_swap_b32 %0, %1" : "+v"(a), "+v"(b));
}
__device__ __forceinline__ float plswap_add(float a, float b) {
    unsigned ua = __float_as_uint(a), ub = __float_as_uint(b);
    plswap(ua, ub);
    return __uint_as_float(ua) + __uint_as_float(ub);
}

// 4 pre-activations (already *2*log2e) -> tanh -> 2 packed bf16 words
__device__ __forceinline__ void quad_tanh_pack(float y0, float y1, float y2, float y3,
                                               unsigned &wlo, unsigned &whi) {
    float s0 = __builtin_amdgcn_rcpf(1.0f + __builtin_amdgcn_exp2f(y0));
    float s1 = __builtin_amdgcn_rcpf(1.0f + __builtin_amdgcn_exp2f(y1));
    float s2 = __builtin_amdgcn_rcpf(1.0f + __builtin_amdgcn_exp2f(y2));
    float s3 = __builtin_amdgcn_rcpf(1.0f + __builtin_amdgcn_exp2f(y3));
    float h0 = fmaf(-2.0f, s0, 1.0f), h1 = fmaf(-2.0f, s1, 1.0f);
    float h2 = fmaf(-2.0f, s2, 1.0f), h3 = fmaf(-2.0f, s3, 1.0f);
    wlo = cvt_pk_bf16(h0, h1);
    whi = cvt_pk_bf16(h2, h3);
}

// layer2 MFMA (combined A: ET rows 0-15 / Q rows 16-31) + sigma-folded fp32 dot.
// BASE=0 reads C regs 0..7 (ET rows), BASE=8 reads regs 8..15 (Q rows).
template <int BASE>
__device__ __forceinline__ float tail(const FragU a2, const float jb[8],
                                      const float w3n[8], float pinit,
                                      const FragU ba, const FragU bb) {
    f32x16 c0, c1;
#pragma unroll
    for (int r = 0; r < 16; ++r) { c0[r] = 0.0f; c1[r] = 0.0f; }
#pragma unroll
    for (int r = 0; r < 8; ++r) { c0[BASE + r] = jb[r]; c1[BASE + r] = jb[r]; }
    c0 = __builtin_amdgcn_mfma_f32_32x32x16_bf16(a2.f, ba.f, c0, 0, 0, 0);
    c1 = __builtin_amdgcn_mfma_f32_32x32x16_bf16(a2.f, bb.f, c1, 0, 0, 0);

    float p0 = pinit, p1 = pinit;
#pragma unroll
    for (int r = 0; r < 8; ++r) {
        float s0 = __builtin_amdgcn_rcpf(1.0f + __builtin_amdgcn_exp2f(c0[BASE + r]));
        float s1 = __builtin_amdgcn_rcpf(1.0f + __builtin_amdgcn_exp2f(c1[BASE + r]));
        p0 = fmaf(w3n[r], s0, p0);
        p1 = fmaf(w3n[r], s1, p1);
    }
    return plswap_add(p0, p1);
}

struct Weights {
    FragU a2;                       // combined: ET rows 0-15, Q rows 16-31
    float jbe[8], jbq[8], w3ne[8], w3nq[8];
    float pinit_e, pinit_q;
    float Df, Tmax, Tmin;
};

__device__ __forceinline__ float2 sample_pipeline(
    float tv, float S_snow, float S_water,
    const float4* __restrict__ s_tbl, const Weights &W,
    const float* __restrict__ g_ew1, const float* __restrict__ g_eb1,
    const float* __restrict__ g_qw1, const float* __restrict__ g_qb1)
{
    int idx = (int)tv;
    idx = max(0, min(idx, TLEN - 2));
    const float fr = tv - (float)idx;
    const float4 t0 = s_tbl[idx];
    const float4 t1 = s_tbl[idx + 1];
    const float precp = fmaf(fr, t1.x - t0.x, t0.x);
    const float temp  = fmaf(fr, t1.y - t0.y, t0.y);
    const float lday  = fmaf(fr, t1.z - t0.z, t0.z);

    // ===== layer1 (fp32, sample-major), fused quad->pack =====
    unsigned elo[4], ehi[4], qlo[4], qhi[4];
#pragma unroll
    for (int j4 = 0; j4 < 4; ++j4) {
        float4 b4 = *reinterpret_cast<const float4*>(&g_eb1[j4 * 4]);
        float4 w0 = *reinterpret_cast<const float4*>(&g_ew1[0 * 16 + j4 * 4]);
        float4 w1 = *reinterpret_cast<const float4*>(&g_ew1[1 * 16 + j4 * 4]);
        float4 w2 = *reinterpret_cast<const float4*>(&g_ew1[2 * 16 + j4 * 4]);
        float y0 = TWO_L2E * fmaf(temp, w2.x, fmaf(S_water, w1.x, fmaf(S_snow, w0.x, b4.x)));
        float y1 = TWO_L2E * fmaf(temp, w2.y, fmaf(S_water, w1.y, fmaf(S_snow, w0.y, b4.y)));
        float y2 = TWO_L2E * fmaf(temp, w2.z, fmaf(S_water, w1.z, fmaf(S_snow, w0.z, b4.z)));
        float y3 = TWO_L2E * fmaf(temp, w2.w, fmaf(S_water, w1.w, fmaf(S_snow, w0.w, b4.w)));
        unsigned wl, wh;
        quad_tanh_pack(y0, y1, y2, y3, wl, wh);
        if (j4 < 2) { elo[j4 * 2] = wl; elo[j4 * 2 + 1] = wh; }
        else        { ehi[(j4 - 2) * 2] = wl; ehi[(j4 - 2) * 2 + 1] = wh; }
    }
#pragma unroll
    for (int j4 = 0; j4 < 4; ++j4) {
        float4 b4 = *reinterpret_cast<const float4*>(&g_qb1[j4 * 4]);
        float4 w0 = *reinterpret_cast<const float4*>(&g_qw1[0 * 16 + j4 * 4]);
        float4 w1 = *reinterpret_cast<const float4*>(&g_qw1[1 * 16 + j4 * 4]);
        float y0 = TWO_L2E * fmaf(precp, w1.x, fmaf(S_water, w0.x, b4.x));
        float y1 = TWO_L2E * fmaf(precp, w1.y, fmaf(S_water, w0.y, b4.y));
        float y2 = TWO_L2E * fmaf(precp, w1.z, fmaf(S_water, w0.z, b4.z));
        float y3 = TWO_L2E * fmaf(precp, w1.w, fmaf(S_water, w0.w, b4.w));
        unsigned wl, wh;
        quad_tanh_pack(y0, y1, y2, y3, wl, wh);
        if (j4 < 2) { qlo[j4 * 2] = wl; qlo[j4 * 2 + 1] = wh; }
        else        { qhi[(j4 - 2) * 2] = wl; qhi[(j4 - 2) * 2 + 1] = wh; }
    }

    // distribute to the two 32-sample B blocks
    FragU bae, bbe, baq, bbq;
#pragma unroll
    for (int p = 0; p < 4; ++p) {
        unsigned l = elo[p], h = ehi[p];
        plswap(l, h);
        bae.u[p] = l; bbe.u[p] = h;
        l = qlo[p]; h = qhi[p];
        plswap(l, h);
        baq.u[p] = l; bbq.u[p] = h;
    }

    const float ETs = tail<0>(W.a2, W.jbe, W.w3ne, W.pinit_e, bae, bbe);
    const float Qs  = tail<8>(W.a2, W.jbq, W.w3nq, W.pinit_q, baq, bbq);

    // ===== bucket dynamics =====
    const float sw_step = step_fn(S_water);
    const float sp      = step_fn(temp - W.Tmin);
    const float melt = step_fn(temp - W.Tmax) * step_fn(S_snow)
                     * fminf(S_snow, W.Df * (temp - W.Tmax));
    const float dS1 = (1.0f - sp) * precp - melt;
    const float dS2 = sp * precp + melt
                    - sw_step * fmaf(lday, __builtin_amdgcn_exp2f(ETs),
                                     __builtin_amdgcn_exp2f(Qs));
    return make_float2(dS1, dS2);
}

__global__ __launch_bounds__(256, 4) void hydro_kernel(
    const float* __restrict__ g_t,
    const float* __restrict__ g_S,
    const float* __restrict__ g_precp,
    const float* __restrict__ g_temp,
    const float* __restrict__ g_lday,
    const float* __restrict__ g_ew1, const float* __restrict__ g_eb1,
    const float* __restrict__ g_ew2, const float* __restrict__ g_eb2,
    const float* __restrict__ g_ew3, const float* __restrict__ g_eb3,
    const float* __restrict__ g_qw1, const float* __restrict__ g_qb1,
    const float* __restrict__ g_qw2, const float* __restrict__ g_qb2,
    const float* __restrict__ g_qw3, const float* __restrict__ g_qb3,
    const float* __restrict__ g_Df, const float* __restrict__ g_Tmax,
    const float* __restrict__ g_Tmin,
    float* __restrict__ g_out, int B)
{
    __shared__ __align__(16) float4 s_tbl[TLEN];

    const int tx = threadIdx.x;
    for (int i = tx; i < TLEN; i += 256) {
        s_tbl[i] = make_float4(g_precp[i], g_temp[i], g_lday[i], 0.0f);
    }
    __syncthreads();

    const int lane = tx & 63;
    const int m  = lane & 31;     // A-fragment row: <16 -> ET feature m, >=16 -> Q feature m-16
    const int kg = lane >> 5;     // k-group: k = 8*kg + e

    Weights W;
    {
        const float* wsrc = (m < 16) ? g_ew2 : g_qw2;
        const int mm = m & 15;
#pragma unroll
        for (int p = 0; p < 4; ++p) {
            const int k0 = 8 * kg + 2 * p, k1 = k0 + 1;
            W.a2.u[p] = cvt_pk_bf16(TWO_L2E * wsrc[k0 * 16 + mm],
                                    TWO_L2E * wsrc[k1 * 16 + mm]);
        }
    }
    float sum_e = 0.0f, sum_q = 0.0f;
#pragma unroll
    for (int r = 0; r < 8; ++r) {
        const int j = (r & 3) + 8 * (r >> 2) + 4 * kg;   // feature row for reg r (and r+8)
        W.jbe[r] = TWO_L2E * g_eb2[j];
        W.jbq[r] = TWO_L2E * g_qb2[j];
        const float w3e = g_ew3[j], w3q = g_qw3[j];
        sum_e += w3e; sum_q += w3q;
        W.w3ne[r] = -2.0f * L2E * w3e;
        W.w3nq[r] = -2.0f * L2E * w3q;
    }
    W.pinit_e = L2E * fmaf(0.5f, g_eb3[0], sum_e);
    W.pinit_q = L2E * fmaf(0.5f, g_qb3[0], sum_q);

    W.Df   = fminf(fmaxf(g_Df[0],   0.01f), 5.0f);
    W.Tmax = fminf(fmaxf(g_Tmax[0], 0.0f),  3.0f);
    W.Tmin = fminf(fmaxf(g_Tmin[0], -3.0f), 0.0f);

    // two samples per thread: i0 = blk*512 + tx, i1 = i0 + 256
    const int i0 = blockIdx.x * 512 + tx;
    const int i1 = i0 + 256;
    const int c0i = (i0 < B) ? i0 : (B - 1);
    const int c1i = (i1 < B) ? i1 : (B - 1);

    const float tv0 = g_t[c0i];
    const float tv1 = g_t[c1i];
    const float2 Sv0 = reinterpret_cast<const float2*>(g_S)[c0i];
    const float2 Sv1 = reinterpret_cast<const float2*>(g_S)[c1i];

    const float2 r0 = sample_pipeline(tv0, Sv0.x, Sv0.y, s_tbl, W,
                                      g_ew1, g_eb1, g_qw1, g_qb1);
    const float2 r1 = sample_pipeline(tv1, Sv1.x, Sv1.y, s_tbl, W,
                                      g_ew1, g_eb1, g_qw1, g_qb1);

    if (i0 < B) reinterpret_cast<float2*>(g_out)[i0] = r0;
    if (i1 < B) reinterpret_cast<float2*>(g_out)[i1] = r1;
}

extern "C" void kernel_launch(void* const* d_in, const int* in_sizes, int n_in,
                              void* d_out, int out_size, void* d_ws, size_t ws_size,
                              hipStream_t stream)
{
    const int B = in_sizes[0];
    const int block = 256;
    const int grid = (B + 511) / 512;
    hipLaunchKernelGGL(hydro_kernel, dim3(grid), dim3(block), 0, stream,
        (const float*)d_in[0],  // t
        (const float*)d_in[1],  // S
        (const float*)d_in[3],  // precp_series
        (const float*)d_in[4],  // temp_series
        (const float*)d_in[5],  // lday_series
        (const float*)d_in[6],  (const float*)d_in[7],
        (const float*)d_in[8],  (const float*)d_in[9],
        (const float*)d_in[10], (const float*)d_in[11],
        (const float*)d_in[12], (const float*)d_in[13],
        (const float*)d_in[14], (const float*)d_in[15],
        (const float*)d_in[16], (const float*)d_in[17],
        (const float*)d_in[21], // Df
        (const float*)d_in[22], // Tmax
        (const float*)d_in[23], // Tmin
        (float*)d_out, B);
}

// Round 7
// 26.610 us; speedup vs baseline: 1.0475x; 1.0475x over previous
//
#include <hip/hip_runtime.h>

#define TLEN 1461
#define L2E      1.44269504088896340736f
#define TWO_L2E  2.88539008177792681472f

typedef __bf16 bf16x8 __attribute__((ext_vector_type(8)));
typedef float f32x16 __attribute__((ext_vector_type(16)));

union FragU { unsigned u[4]; bf16x8 f; };

__device__ __forceinline__ float step_fn(float x) {
    // (tanh(5x)+1)/2 = sigmoid(10x) = 1/(1+exp2(-10*log2e*x))
    float e = __builtin_amdgcn_exp2f(x * -14.4269504088896341f);
    return __builtin_amdgcn_rcpf(1.0f + e);
}
__device__ __forceinline__ unsigned cvt_pk_bf16(float lo, float hi) {
    unsigned r;
    asm("v_cvt_pk_bf16_f32 %0, %1, %2" : "=v"(r) : "v"(lo), "v"(hi));
    return r;
}
__device__ __forceinline__ void plswap(unsigned &a, unsigned &b) {
    asm("v_permlane32_swap_b32 %0, %1" : "+v"(a), "+v"(b));
}
__device__ __forceinline__ float plswap_add(float a, float b) {
    unsigned ua = __float_as_uint(a), ub = __float_as_uint(b);
    plswap(ua, ub);
    return __uint_as_float(ua) + __uint_as_float(ub);
}

// 4 pre-activations (already *2*log2e) -> tanh -> 2 packed bf16 words
__device__ __forceinline__ void quad_tanh_pack(float y0, float y1, float y2, float y3,
                                               unsigned &wlo, unsigned &whi) {
    float s0 = __builtin_amdgcn_rcpf(1.0f + __builtin_amdgcn_exp2f(y0));
    float s1 = __builtin_amdgcn_rcpf(1.0f + __builtin_amdgcn_exp2f(y1));
    float s2 = __builtin_amdgcn_rcpf(1.0f + __builtin_amdgcn_exp2f(y2));
    float s3 = __builtin_amdgcn_rcpf(1.0f + __builtin_amdgcn_exp2f(y3));
    float h0 = fmaf(-2.0f, s0, 1.0f), h1 = fmaf(-2.0f, s1, 1.0f);
    float h2 = fmaf(-2.0f, s2, 1.0f), h3 = fmaf(-2.0f, s3, 1.0f);
    wlo = cvt_pk_bf16(h0, h1);
    whi = cvt_pk_bf16(h2, h3);
}

// layer2 MFMA (combined A: ET rows 0-15, Q rows 16-31) + sigma-folded fp32 dot.
// Weight constants are REMATERIALIZABLE: uniform s_load (compile-time index)
// + per-lane cndmask on `hi` -- no persistent VGPR arrays, no spill under cap.
// Only c[BASE..BASE+8) initialized; other half left undef (rows unread).
template <int BASE>
__device__ __forceinline__ float tail_slim(const FragU a2,
    const float* __restrict__ b2, const float* __restrict__ w3,
    float pinit, bool hi, const FragU ba, const FragU bb)
{
    f32x16 c0, c1;
#pragma unroll
    for (int r = 0; r < 8; ++r) {
        const int j0 = (r & 3) + 8 * (r >> 2);
        float jb = TWO_L2E * (hi ? b2[j0 + 4] : b2[j0]);
        c0[BASE + r] = jb;
        c1[BASE + r] = jb;
    }
    c0 = __builtin_amdgcn_mfma_f32_32x32x16_bf16(a2.f, ba.f, c0, 0, 0, 0);
    c1 = __builtin_amdgcn_mfma_f32_32x32x16_bf16(a2.f, bb.f, c1, 0, 0, 0);

    float p0 = pinit, p1 = pinit;
#pragma unroll
    for (int r = 0; r < 8; ++r) {
        const int j0 = (r & 3) + 8 * (r >> 2);
        float w3n = -TWO_L2E * (hi ? w3[j0 + 4] : w3[j0]);
        float s0 = __builtin_amdgcn_rcpf(1.0f + __builtin_amdgcn_exp2f(c0[BASE + r]));
        float s1 = __builtin_amdgcn_rcpf(1.0f + __builtin_amdgcn_exp2f(c1[BASE + r]));
        p0 = fmaf(w3n, s0, p0);
        p1 = fmaf(w3n, s1, p1);
    }
    return plswap_add(p0, p1);
}

__device__ __forceinline__ float2 sample_pipeline(
    float tv, float S_snow, float S_water,
    const float4* __restrict__ s_tbl, const FragU a2,
    float pinit_e, float pinit_q, bool hi,
    float Df, float Tmax, float Tmin,
    const float* __restrict__ g_ew1, const float* __restrict__ g_eb1,
    const float* __restrict__ g_eb2, const float* __restrict__ g_ew3,
    const float* __restrict__ g_qw1, const float* __restrict__ g_qb1,
    const float* __restrict__ g_qb2, const float* __restrict__ g_qw3)
{
    int idx = (int)tv;
    idx = max(0, min(idx, TLEN - 2));
    const float fr = tv - (float)idx;
    const float4 t0 = s_tbl[idx];
    const float4 t1 = s_tbl[idx + 1];
    const float precp = fmaf(fr, t1.x - t0.x, t0.x);
    const float temp  = fmaf(fr, t1.y - t0.y, t0.y);
    const float lday  = fmaf(fr, t1.z - t0.z, t0.z);

    // ===== layer1 (fp32, sample-major), fused quad->pack =====
    unsigned elo[4], ehi[4], qlo[4], qhi[4];
#pragma unroll
    for (int j4 = 0; j4 < 4; ++j4) {
        float4 b4 = *reinterpret_cast<const float4*>(&g_eb1[j4 * 4]);
        float4 w0 = *reinterpret_cast<const float4*>(&g_ew1[0 * 16 + j4 * 4]);
        float4 w1 = *reinterpret_cast<const float4*>(&g_ew1[1 * 16 + j4 * 4]);
        float4 w2 = *reinterpret_cast<const float4*>(&g_ew1[2 * 16 + j4 * 4]);
        float y0 = TWO_L2E * fmaf(temp, w2.x, fmaf(S_water, w1.x, fmaf(S_snow, w0.x, b4.x)));
        float y1 = TWO_L2E * fmaf(temp, w2.y, fmaf(S_water, w1.y, fmaf(S_snow, w0.y, b4.y)));
        float y2 = TWO_L2E * fmaf(temp, w2.z, fmaf(S_water, w1.z, fmaf(S_snow, w0.z, b4.z)));
        float y3 = TWO_L2E * fmaf(temp, w2.w, fmaf(S_water, w1.w, fmaf(S_snow, w0.w, b4.w)));
        unsigned wl, wh;
        quad_tanh_pack(y0, y1, y2, y3, wl, wh);
        if (j4 < 2) { elo[j4 * 2] = wl; elo[j4 * 2 + 1] = wh; }
        else        { ehi[(j4 - 2) * 2] = wl; ehi[(j4 - 2) * 2 + 1] = wh; }
    }
#pragma unroll
    for (int j4 = 0; j4 < 4; ++j4) {
        float4 b4 = *reinterpret_cast<const float4*>(&g_qb1[j4 * 4]);
        float4 w0 = *reinterpret_cast<const float4*>(&g_qw1[0 * 16 + j4 * 4]);
        float4 w1 = *reinterpret_cast<const float4*>(&g_qw1[1 * 16 + j4 * 4]);
        float y0 = TWO_L2E * fmaf(precp, w1.x, fmaf(S_water, w0.x, b4.x));
        float y1 = TWO_L2E * fmaf(precp, w1.y, fmaf(S_water, w0.y, b4.y));
        float y2 = TWO_L2E * fmaf(precp, w1.z, fmaf(S_water, w0.z, b4.z));
        float y3 = TWO_L2E * fmaf(precp, w1.w, fmaf(S_water, w0.w, b4.w));
        unsigned wl, wh;
        quad_tanh_pack(y0, y1, y2, y3, wl, wh);
        if (j4 < 2) { qlo[j4 * 2] = wl; qlo[j4 * 2 + 1] = wh; }
        else        { qhi[(j4 - 2) * 2] = wl; qhi[(j4 - 2) * 2 + 1] = wh; }
    }

    // distribute to the two 32-sample B blocks
    FragU bae, bbe, baq, bbq;
#pragma unroll
    for (int p = 0; p < 4; ++p) {
        unsigned l = elo[p], h = ehi[p];
        plswap(l, h);
        bae.u[p] = l; bbe.u[p] = h;
        l = qlo[p]; h = qhi[p];
        plswap(l, h);
        baq.u[p] = l; bbq.u[p] = h;
    }

    const float ETs = tail_slim<0>(a2, g_eb2, g_ew3, pinit_e, hi, bae, bbe);
    const float Qs  = tail_slim<8>(a2, g_qb2, g_qw3, pinit_q, hi, baq, bbq);

    // ===== bucket dynamics =====
    const float sw_step = step_fn(S_water);
    const float sp      = step_fn(temp - Tmin);
    const float melt = step_fn(temp - Tmax) * step_fn(S_snow)
                     * fminf(S_snow, Df * (temp - Tmax));
    const float dS1 = (1.0f - sp) * precp - melt;
    const float dS2 = sp * precp + melt
                    - sw_step * fmaf(lday, __builtin_amdgcn_exp2f(ETs),
                                     __builtin_amdgcn_exp2f(Qs));
    return make_float2(dS1, dS2);
}

__global__ __launch_bounds__(256, 4) void hydro_kernel(
    const float* __restrict__ g_t,
    const float* __restrict__ g_S,
    const float* __restrict__ g_precp,
    const float* __restrict__ g_temp,
    const float* __restrict__ g_lday,
    const float* __restrict__ g_ew1, const float* __restrict__ g_eb1,
    const float* __restrict__ g_ew2, const float* __restrict__ g_eb2,
    const float* __restrict__ g_ew3, const float* __restrict__ g_eb3,
    const float* __restrict__ g_qw1, const float* __restrict__ g_qb1,
    const float* __restrict__ g_qw2, const float* __restrict__ g_qb2,
    const float* __restrict__ g_qw3, const float* __restrict__ g_qb3,
    const float* __restrict__ g_Df, const float* __restrict__ g_Tmax,
    const float* __restrict__ g_Tmin,
    float* __restrict__ g_out, int B)
{
    __shared__ __align__(16) float4 s_tbl[TLEN];

    const int tx = threadIdx.x;
    for (int i = tx; i < TLEN; i += 256) {
        s_tbl[i] = make_float4(g_precp[i], g_temp[i], g_lday[i], 0.0f);
    }
    __syncthreads();

    const int lane = tx & 63;
    const int m  = lane & 31;     // A row: <16 -> ET feature m, >=16 -> Q feature m-16
    const bool hi = (lane >> 5) != 0;   // k-group / C-row-half select

    // combined A-fragment (4 VGPRs, one-time scattered loads)
    FragU a2;
    {
        const float* wsrc = (m < 16) ? g_ew2 : g_qw2;
        const int mm = m & 15;
        const int kg8 = hi ? 8 : 0;
#pragma unroll
        for (int p = 0; p < 4; ++p) {
            const int k0 = kg8 + 2 * p, k1 = k0 + 1;
            a2.u[p] = cvt_pk_bf16(TWO_L2E * wsrc[k0 * 16 + mm],
                                  TWO_L2E * wsrc[k1 * 16 + mm]);
        }
    }

    // uniform row-sums of w3 (SGPR-resident), pinit = l2e*(0.5*b3 + sum8(w3 rows))
    float slo_e = 0.0f, shi_e = 0.0f, slo_q = 0.0f, shi_q = 0.0f;
#pragma unroll
    for (int r = 0; r < 8; ++r) {
        const int j0 = (r & 3) + 8 * (r >> 2);
        slo_e += g_ew3[j0]; shi_e += g_ew3[j0 + 4];
        slo_q += g_qw3[j0]; shi_q += g_qw3[j0 + 4];
    }
    const float pinit_e = L2E * fmaf(0.5f, g_eb3[0], hi ? shi_e : slo_e);
    const float pinit_q = L2E * fmaf(0.5f, g_qb3[0], hi ? shi_q : slo_q);

    const float Df   = fminf(fmaxf(g_Df[0],   0.01f), 5.0f);
    const float Tmax = fminf(fmaxf(g_Tmax[0], 0.0f),  3.0f);
    const float Tmin = fminf(fmaxf(g_Tmin[0], -3.0f), 0.0f);

    // two samples per thread: i0 = blk*512 + tx, i1 = i0 + 256
    const int i0 = blockIdx.x * 512 + tx;
    const int i1 = i0 + 256;
    const int c0i = (i0 < B) ? i0 : (B - 1);
    const int c1i = (i1 < B) ? i1 : (B - 1);

    const float tv0 = g_t[c0i];
    const float tv1 = g_t[c1i];
    const float2 Sv0 = reinterpret_cast<const float2*>(g_S)[c0i];
    const float2 Sv1 = reinterpret_cast<const float2*>(g_S)[c1i];

    const float2 r0 = sample_pipeline(tv0, Sv0.x, Sv0.y, s_tbl, a2,
                                      pinit_e, pinit_q, hi, Df, Tmax, Tmin,
                                      g_ew1, g_eb1, g_eb2, g_ew3,
                                      g_qw1, g_qb1, g_qb2, g_qw3);
    const float2 r1 = sample_pipeline(tv1, Sv1.x, Sv1.y, s_tbl, a2,
                                      pinit_e, pinit_q, hi, Df, Tmax, Tmin,
                                      g_ew1, g_eb1, g_eb2, g_ew3,
                                      g_qw1, g_qb1, g_qb2, g_qw3);

    if (i0 < B) reinterpret_cast<float2*>(g_out)[i0] = r0;
    if (i1 < B) reinterpret_cast<float2*>(g_out)[i1] = r1;
}

extern "C" void kernel_launch(void* const* d_in, const int* in_sizes, int n_in,
                              void* d_out, int out_size, void* d_ws, size_t ws_size,
                              hipStream_t stream)
{
    const int B = in_sizes[0];
    const int block = 256;
    const int grid = (B + 511) / 512;
    hipLaunchKernelGGL(hydro_kernel, dim3(grid), dim3(block), 0, stream,
        (const float*)d_in[0],  // t
        (const float*)d_in[1],  // S
        (const float*)d_in[3],  // precp_series
        (const float*)d_in[4],  // temp_series
        (const float*)d_in[5],  // lday_series
        (const float*)d_in[6],  (const float*)d_in[7],
        (const float*)d_in[8],  (const float*)d_in[9],
        (const float*)d_in[10], (const float*)d_in[11],
        (const float*)d_in[12], (const float*)d_in[13],
        (const float*)d_in[14], (const float*)d_in[15],
        (const float*)d_in[16], (const float*)d_in[17],
        (const float*)d_in[21], // Df
        (const float*)d_in[22], // Tmax
        (const float*)d_in[23], // Tmin
        (float*)d_out, B);
}